// Round 7
// baseline (362.044 us; speedup 1.0000x reference)
//
#include <hip/hip_runtime.h>
#include <cstdint>

typedef __bf16 bf16;
typedef __bf16 bf16x8 __attribute__((ext_vector_type(8)));
typedef __bf16 bf16x4 __attribute__((ext_vector_type(4)));
typedef float  f32x4  __attribute__((ext_vector_type(4)));

#define MFMA_BF16(a, b, c) __builtin_amdgcn_mfma_f32_16x16x32_bf16(a, b, c, 0, 0, 0)

// async global->LDS, 16B/lane; LDS dest must be wave-uniform base + lane*16 (verified: r1==r2 bitwise).
__device__ __forceinline__ void async_load16(const void* g, void* l) {
    __builtin_amdgcn_global_load_lds(
        (__attribute__((address_space(1))) uint32_t*)(uintptr_t)g,
        (__attribute__((address_space(3))) uint32_t*)(uint32_t)(uintptr_t)l,
        16, 0, 0);
}

// ---------------- fp32 -> bf16 convert ----------------
__global__ void cvt_kernel(const float* __restrict__ src, bf16* __restrict__ dst, int n4) {
    int i = blockIdx.x * blockDim.x + threadIdx.x;
    if (i < n4) {
        float4 v = ((const float4*)src)[i];
        bf16x4 o;
        o[0] = (bf16)v.x; o[1] = (bf16)v.y; o[2] = (bf16)v.z; o[3] = (bf16)v.w;
        ((bf16x4*)dst)[i] = o;
    }
}

// ---------------- QKV GEMM (async staging): C = x_bf @ wq_bf^T + b, scatter Q/K/Vt ----------------
__global__ __launch_bounds__(256) void gemm_qkv_kernel(
    const bf16* __restrict__ A,     // [4096,1024]
    const bf16* __restrict__ W,     // [3072,1024]
    const float* __restrict__ bias, // [3072]
    bf16* __restrict__ Qb, bf16* __restrict__ Kb, bf16* __restrict__ Vt)
{
    const int Kd = 1024;
    __shared__ bf16 sA[128 * 32];
    __shared__ bf16 sB[128 * 32];
    int tid = threadIdx.x, lane = tid & 63, wid = tid >> 6;
    int m0 = blockIdx.y * 128, n0 = blockIdx.x * 128;
    int srow = wid * 32 + (lane >> 2);
    int scol = (lane & 3) * 8;
    const bf16* Ag = A + (size_t)(m0 + srow) * Kd + scol;
    const bf16* Wg = W + (size_t)(n0 + srow) * Kd + scol;
    bf16* sAp = &sA[srow * 32 + scol];
    bf16* sBp = &sB[srow * 32 + scol];
    int wm = (wid & 1) * 64, wn = (wid >> 1) * 64;
    int lcol = lane & 15, quad = lane >> 4;
    f32x4 acc[4][4] = {};
    for (int k0 = 0; k0 < Kd; k0 += 32) {
        __syncthreads();
        async_load16(Ag + k0, sAp);
        async_load16(Ag + k0 + 16 * Kd, sAp + 16 * 32);
        async_load16(Wg + k0, sBp);
        async_load16(Wg + k0 + 16 * Kd, sBp + 16 * 32);
        __syncthreads();
        bf16x8 af[4], bfr[4];
#pragma unroll
        for (int i = 0; i < 4; i++)
            af[i] = *(const bf16x8*)&sA[(wm + i * 16 + lcol) * 32 + quad * 8];
#pragma unroll
        for (int i = 0; i < 4; i++)
            bfr[i] = *(const bf16x8*)&sB[(wn + i * 16 + lcol) * 32 + quad * 8];
#pragma unroll
        for (int i = 0; i < 4; i++)
#pragma unroll
            for (int j = 0; j < 4; j++)
                acc[i][j] = MFMA_BF16(af[i], bfr[j], acc[i][j]);
    }
#pragma unroll
    for (int j = 0; j < 4; j++) {
        int n = n0 + wn + j * 16 + lcol;
        float bv = bias[n];
        int part = n >> 10, d = n & 1023, h = d >> 6, dd = d & 63;
#pragma unroll
        for (int i = 0; i < 4; i++) {
            int mb = m0 + wm + i * 16 + quad * 4;
            int b = mb >> 10, s = mb & 1023;
            if (part == 2) {
                bf16x4 v4;
#pragma unroll
                for (int r = 0; r < 4; r++) v4[r] = (bf16)(acc[i][j][r] + bv);
                *(bf16x4*)&Vt[(size_t)((b * 16 + h) * 64 + dd) * 1024 + s] = v4;
            } else {
                float scv = (part == 0) ? 0.125f : 1.0f;
                bf16* dst = (part == 0 ? Qb : Kb) + (size_t)((b * 16 + h) * 1024 + s) * 64 + dd;
#pragma unroll
                for (int r = 0; r < 4; r++) dst[(size_t)r * 64] = (bf16)((acc[i][j][r] + bv) * scv);
            }
        }
    }
}

// ---------------- out-proj GEMM (async staging): ao = ctx @ wo_bf^T + b (fp32 out) ----------------
__global__ __launch_bounds__(256) void gemm_out_kernel(
    const bf16* __restrict__ A,     // ctx [4096,1024]
    const bf16* __restrict__ W,     // [1024,1024]
    const float* __restrict__ bias, // [1024]
    float* __restrict__ out)        // [4096,1024] fp32
{
    const int Kd = 1024;
    __shared__ bf16 sA[128 * 32];
    __shared__ bf16 sB[128 * 32];
    int tid = threadIdx.x, lane = tid & 63, wid = tid >> 6;
    int m0 = blockIdx.y * 128, n0 = blockIdx.x * 128;
    int srow = wid * 32 + (lane >> 2);
    int scol = (lane & 3) * 8;
    const bf16* Ag = A + (size_t)(m0 + srow) * Kd + scol;
    const bf16* Wg = W + (size_t)(n0 + srow) * Kd + scol;
    bf16* sAp = &sA[srow * 32 + scol];
    bf16* sBp = &sB[srow * 32 + scol];
    int wm = (wid & 1) * 64, wn = (wid >> 1) * 64;
    int lcol = lane & 15, quad = lane >> 4;
    f32x4 acc[4][4] = {};
    for (int k0 = 0; k0 < Kd; k0 += 32) {
        __syncthreads();
        async_load16(Ag + k0, sAp);
        async_load16(Ag + k0 + 16 * Kd, sAp + 16 * 32);
        async_load16(Wg + k0, sBp);
        async_load16(Wg + k0 + 16 * Kd, sBp + 16 * 32);
        __syncthreads();
        bf16x8 af[4], bfr[4];
#pragma unroll
        for (int i = 0; i < 4; i++)
            af[i] = *(const bf16x8*)&sA[(wm + i * 16 + lcol) * 32 + quad * 8];
#pragma unroll
        for (int i = 0; i < 4; i++)
            bfr[i] = *(const bf16x8*)&sB[(wn + i * 16 + lcol) * 32 + quad * 8];
#pragma unroll
        for (int i = 0; i < 4; i++)
#pragma unroll
            for (int j = 0; j < 4; j++)
                acc[i][j] = MFMA_BF16(af[i], bfr[j], acc[i][j]);
    }
#pragma unroll
    for (int j = 0; j < 4; j++) {
        int n = n0 + wn + j * 16 + lcol;
        float bv = bias[n];
#pragma unroll
        for (int i = 0; i < 4; i++) {
            int m = m0 + wm + i * 16 + quad * 4;
#pragma unroll
            for (int r = 0; r < 4; r++) out[(size_t)(m + r) * 1024 + n] = acc[i][j][r] + bv;
        }
    }
}

// ---------------- fused attention: 2-pass register-flash, 2 barriers/head ----------------
// grid 1024: b = bx>>8, q0 = ((bx>>2)&63)*16, g = bx&3 (heads g*4..g*4+3)
#define SD 1032
__global__ __launch_bounds__(256) void attn_kernel(
    const bf16* __restrict__ Qb, const bf16* __restrict__ Kb, const bf16* __restrict__ Vt,
    bf16* __restrict__ ctx, bf16* __restrict__ pw)
{
    __shared__ bf16 sc[16 * SD];
    __shared__ float redm[16][4];
    __shared__ float redl[16][4];
    int tid = threadIdx.x, lane = tid & 63, wid = tid >> 6;
    int bx = blockIdx.x;
    int g = bx & 3;
    int q0 = ((bx >> 2) & 63) * 16;
    int b = bx >> 8;
    int lcol = lane & 15, quad = lane >> 4;
    float acc_w[64];
#pragma unroll
    for (int i = 0; i < 64; i++) acc_w[i] = 0.f;

    for (int hh = 0; hh < 4; hh++) {
        int h = g * 4 + hh;
        size_t base = (size_t)(b * 16 + h) * 1024 * 64;
        const bf16* qp = Qb + base + (size_t)(q0 + lcol) * 64 + quad * 8;
        bf16x8 a0 = *(const bf16x8*)qp;
        bf16x8 a1 = *(const bf16x8*)(qp + 32);
        const bf16* kp = Kb + base;

        // ---- pass A: QK^T in registers, row-max (no LDS, overlaps prev head's PV) ----
        float rmax[4] = {-1e30f, -1e30f, -1e30f, -1e30f};
#pragma unroll
        for (int nt = 0; nt < 16; nt++) {
            int n0 = wid * 256 + nt * 16;
            const bf16* kr = kp + (size_t)(n0 + lcol) * 64 + quad * 8;
            bf16x8 b0 = *(const bf16x8*)kr;
            bf16x8 b1 = *(const bf16x8*)(kr + 32);
            f32x4 s = {};
            s = MFMA_BF16(a0, b0, s);
            s = MFMA_BF16(a1, b1, s);
#pragma unroll
            for (int rr = 0; rr < 4; rr++) rmax[rr] = fmaxf(rmax[rr], s[rr]);
        }
#pragma unroll
        for (int mk = 1; mk < 16; mk <<= 1)
#pragma unroll
            for (int rr = 0; rr < 4; rr++)
                rmax[rr] = fmaxf(rmax[rr], __shfl_xor(rmax[rr], mk, 64));
        if (lcol == 0) {
#pragma unroll
            for (int rr = 0; rr < 4; rr++) redm[quad * 4 + rr][wid] = rmax[rr];
        }
        __syncthreads();  // B1: redm visible; prev head's PV reads of sc complete
        float mrow[4];
#pragma unroll
        for (int rr = 0; rr < 4; rr++) {
            int row = quad * 4 + rr;
            mrow[rr] = fmaxf(fmaxf(redm[row][0], redm[row][1]),
                             fmaxf(redm[row][2], redm[row][3]));
        }

        // ---- pass B: recompute, e = exp(s-m) -> regs + LDS, l partial ----
        bf16 e_reg[64];
        float lp[4] = {0.f, 0.f, 0.f, 0.f};
#pragma unroll
        for (int nt = 0; nt < 16; nt++) {
            int n0 = wid * 256 + nt * 16;
            const bf16* kr = kp + (size_t)(n0 + lcol) * 64 + quad * 8;
            bf16x8 b0 = *(const bf16x8*)kr;
            bf16x8 b1 = *(const bf16x8*)(kr + 32);
            f32x4 s = {};
            s = MFMA_BF16(a0, b0, s);
            s = MFMA_BF16(a1, b1, s);
#pragma unroll
            for (int rr = 0; rr < 4; rr++) {
                float ev = __expf(s[rr] - mrow[rr]);
                lp[rr] += ev;
                bf16 eb = (bf16)ev;
                e_reg[nt * 4 + rr] = eb;
                sc[(quad * 4 + rr) * SD + n0 + lcol] = eb;
            }
        }
#pragma unroll
        for (int mk = 1; mk < 16; mk <<= 1)
#pragma unroll
            for (int rr = 0; rr < 4; rr++) lp[rr] += __shfl_xor(lp[rr], mk, 64);
        if (lcol == 0) {
#pragma unroll
            for (int rr = 0; rr < 4; rr++) redl[quad * 4 + rr][wid] = lp[rr];
        }
        __syncthreads();  // B2: e-LDS + redl visible
        float invl[4];
#pragma unroll
        for (int rr = 0; rr < 4; rr++) {
            int row = quad * 4 + rr;
            invl[rr] = 1.f / (redl[row][0] + redl[row][1] + redl[row][2] + redl[row][3]);
        }
        // head-mean accumulate from registers
#pragma unroll
        for (int nt = 0; nt < 16; nt++)
#pragma unroll
            for (int rr = 0; rr < 4; rr++)
                acc_w[rr * 16 + nt] += (float)e_reg[nt * 4 + rr] * invl[rr];
        // ---- PV ----
        const bf16* vp = Vt + (size_t)(b * 16 + h) * 64 * 1024 + (size_t)(wid * 16 + lcol) * 1024 + quad * 8;
        f32x4 o = {};
#pragma unroll
        for (int kt = 0; kt < 32; kt++) {
            bf16x8 pa = *(const bf16x8*)&sc[lcol * SD + kt * 32 + quad * 8];
            bf16x8 vb = *(const bf16x8*)(vp + (size_t)kt * 32);
            o = MFMA_BF16(pa, vb, o);
        }
#pragma unroll
        for (int rr = 0; rr < 4; rr++) {
            ctx[(size_t)(b * 1024 + q0 + quad * 4 + rr) * 1024 + h * 64 + wid * 16 + lcol] =
                (bf16)(o[rr] * invl[rr]);
        }
    }
    // ---- pw repack (coalesced) ----
    __syncthreads();  // last PV sc reads done
#pragma unroll
    for (int nt = 0; nt < 16; nt++)
#pragma unroll
        for (int rr = 0; rr < 4; rr++)
            sc[(quad * 4 + rr) * 1024 + wid * 256 + nt * 16 + lcol] =
                (bf16)(acc_w[rr * 16 + nt] * 0.0625f);
    __syncthreads();
    bf16* outp = pw + ((size_t)(g * 4 + b) * 1024 + q0) * 1024;
#pragma unroll
    for (int j = 0; j < 8; j++)
        *(bf16x8*)(outp + j * 2048 + tid * 8) = *(const bf16x8*)&sc[j * 2048 + tid * 8];
}

// ---------------- combine 4 head-group partials -> fp32 aw ----------------
__global__ __launch_bounds__(256) void combine_kernel(const bf16* __restrict__ pw, float* __restrict__ aw) {
    const size_t NP = 4ull * 1024 * 1024;
    size_t i = ((size_t)blockIdx.x * 256 + threadIdx.x) * 8;
    bf16x8 p0 = *(const bf16x8*)(pw + i);
    bf16x8 p1 = *(const bf16x8*)(pw + NP + i);
    bf16x8 p2 = *(const bf16x8*)(pw + 2 * NP + i);
    bf16x8 p3 = *(const bf16x8*)(pw + 3 * NP + i);
    float4 lo, hi;
    lo.x = (float)p0[0] + (float)p1[0] + (float)p2[0] + (float)p3[0];
    lo.y = (float)p0[1] + (float)p1[1] + (float)p2[1] + (float)p3[1];
    lo.z = (float)p0[2] + (float)p1[2] + (float)p2[2] + (float)p3[2];
    lo.w = (float)p0[3] + (float)p1[3] + (float)p2[3] + (float)p3[3];
    hi.x = (float)p0[4] + (float)p1[4] + (float)p2[4] + (float)p3[4];
    hi.y = (float)p0[5] + (float)p1[5] + (float)p2[5] + (float)p3[5];
    hi.z = (float)p0[6] + (float)p1[6] + (float)p2[6] + (float)p3[6];
    hi.w = (float)p0[7] + (float)p1[7] + (float)p2[7] + (float)p3[7];
    *(float4*)(aw + i)     = lo;
    *(float4*)(aw + i + 4) = hi;
}

// ---------------- residual + LayerNorm (fp32 output) ----------------
__global__ __launch_bounds__(256) void ln_kernel(
    const float* __restrict__ x, const float* __restrict__ ao,
    const float* __restrict__ w, const float* __restrict__ bsh,
    float* __restrict__ y)
{
    int row = blockIdx.x, tid = threadIdx.x;
    float4 xv = ((const float4*)(x + (size_t)row * 1024))[tid];
    float4 av = ((const float4*)(ao + (size_t)row * 1024))[tid];
    float4 v = {xv.x + av.x, xv.y + av.y, xv.z + av.z, xv.w + av.w};
    float s = v.x + v.y + v.z + v.w;
    float ss = v.x * v.x + v.y * v.y + v.z * v.z + v.w * v.w;
#pragma unroll
    for (int off = 32; off; off >>= 1) { s += __shfl_down(s, off); ss += __shfl_down(ss, off); }
    __shared__ float rs[4], rss[4];
    int lane = tid & 63, wid = tid >> 6;
    if (lane == 0) { rs[wid] = s; rss[wid] = ss; }
    __syncthreads();
    s = rs[0] + rs[1] + rs[2] + rs[3];
    ss = rss[0] + rss[1] + rss[2] + rss[3];
    float mean = s * (1.f / 1024.f);
    float var = ss * (1.f / 1024.f) - mean * mean;
    float inv = rsqrtf(var + 1e-5f);
    float4 wv = ((const float4*)w)[tid];
    float4 bv = ((const float4*)bsh)[tid];
    float4 o;
    o.x = (v.x - mean) * inv * wv.x + bv.x;
    o.y = (v.y - mean) * inv * wv.y + bv.y;
    o.z = (v.z - mean) * inv * wv.z + bv.z;
    o.w = (v.w - mean) * inv * wv.w + bv.w;
    ((float4*)y)[row * 256 + tid] = o;
}

extern "C" void kernel_launch(void* const* d_in, const int* in_sizes, int n_in,
                              void* d_out, int out_size, void* d_ws, size_t ws_size,
                              hipStream_t stream) {
    const float* x     = (const float*)d_in[0];
    const float* w_qkv = (const float*)d_in[1];
    const float* b_qkv = (const float*)d_in[2];
    const float* w_out = (const float*)d_in[3];
    const float* b_out = (const float*)d_in[4];
    const float* ln_w  = (const float*)d_in[5];
    const float* ln_b  = (const float*)d_in[6];

    char* ws = (char*)d_ws;
    // 64 MiB peak with liveness overlays:
    // [0,8M) Qb | [8,16M) Kb | [16,24M) Vt | [24,32M) ctx | [32,64M) pw
    // x_bf [32,40M), wq_bf [40,46M): live only cvt->gemm_qkv (pw region free then)
    // wo_bf [16,18M): cvt after attn (Vt dead); ao fp32 [0,16M) after attn (Qb/Kb dead)
    bf16*  Qb    = (bf16*)(ws);
    bf16*  Kb    = (bf16*)(ws + (8ull  << 20));
    bf16*  Vt    = (bf16*)(ws + (16ull << 20));
    bf16*  ctx   = (bf16*)(ws + (24ull << 20));
    bf16*  pw    = (bf16*)(ws + (32ull << 20));
    bf16*  x_bf  = (bf16*)(ws + (32ull << 20));
    bf16*  wq_bf = (bf16*)(ws + (40ull << 20));
    bf16*  wo_bf = (bf16*)(ws + (16ull << 20));
    float* ao    = (float*)(ws);

    float* y_out  = (float*)d_out;
    float* aw_out = y_out + 4ull * 1024 * 1024;

    cvt_kernel<<<4096, 256, 0, stream>>>(x, x_bf, 1048576);
    cvt_kernel<<<3072, 256, 0, stream>>>(w_qkv, wq_bf, 786432);
    gemm_qkv_kernel<<<dim3(24, 32), 256, 0, stream>>>(x_bf, wq_bf, b_qkv, Qb, Kb, Vt);
    attn_kernel<<<1024, 256, 0, stream>>>(Qb, Kb, Vt, ctx, pw);
    combine_kernel<<<2048, 256, 0, stream>>>(pw, aw_out);
    cvt_kernel<<<1024, 256, 0, stream>>>(w_out, wo_bf, 262144);
    gemm_out_kernel<<<dim3(8, 32), 256, 0, stream>>>(ctx, wo_bf, b_out, ao);
    ln_kernel<<<4096, 256, 0, stream>>>(x, ao, ln_w, ln_b, y_out);
}

// Round 9
// 346.989 us; speedup vs baseline: 1.0434x; 1.0434x over previous
//
#include <hip/hip_runtime.h>
#include <cstdint>

typedef __bf16 bf16;
typedef __bf16 bf16x8 __attribute__((ext_vector_type(8)));
typedef __bf16 bf16x4 __attribute__((ext_vector_type(4)));
typedef float  f32x4  __attribute__((ext_vector_type(4)));

#define MFMA_BF16(a, b, c) __builtin_amdgcn_mfma_f32_16x16x32_bf16(a, b, c, 0, 0, 0)

// async global->LDS, 16B/lane; LDS dest must be wave-uniform base + lane*16.
__device__ __forceinline__ void async_load16(const void* g, void* l) {
    __builtin_amdgcn_global_load_lds(
        (__attribute__((address_space(1))) uint32_t*)(uintptr_t)g,
        (__attribute__((address_space(3))) uint32_t*)(uint32_t)(uintptr_t)l,
        16, 0, 0);
}

// ---------------- fp32 -> bf16 convert ----------------
__global__ void cvt_kernel(const float* __restrict__ src, bf16* __restrict__ dst, int n4) {
    int i = blockIdx.x * blockDim.x + threadIdx.x;
    if (i < n4) {
        float4 v = ((const float4*)src)[i];
        bf16x4 o;
        o[0] = (bf16)v.x; o[1] = (bf16)v.y; o[2] = (bf16)v.z; o[3] = (bf16)v.w;
        ((bf16x4*)dst)[i] = o;
    }
}

// ---------------- QKV GEMM (async staging): scatter Q/K/Vt ----------------
__global__ __launch_bounds__(256) void gemm_qkv_kernel(
    const bf16* __restrict__ A, const bf16* __restrict__ W,
    const float* __restrict__ bias,
    bf16* __restrict__ Qb, bf16* __restrict__ Kb, bf16* __restrict__ Vt)
{
    const int Kd = 1024;
    __shared__ bf16 sA[128 * 32];
    __shared__ bf16 sB[128 * 32];
    int tid = threadIdx.x, lane = tid & 63, wid = tid >> 6;
    int m0 = blockIdx.y * 128, n0 = blockIdx.x * 128;
    int srow = wid * 32 + (lane >> 2);
    int scol = (lane & 3) * 8;
    const bf16* Ag = A + (size_t)(m0 + srow) * Kd + scol;
    const bf16* Wg = W + (size_t)(n0 + srow) * Kd + scol;
    bf16* sAp = &sA[srow * 32 + scol];
    bf16* sBp = &sB[srow * 32 + scol];
    int wm = (wid & 1) * 64, wn = (wid >> 1) * 64;
    int lcol = lane & 15, quad = lane >> 4;
    f32x4 acc[4][4] = {};
    for (int k0 = 0; k0 < Kd; k0 += 32) {
        __syncthreads();
        async_load16(Ag + k0, sAp);
        async_load16(Ag + k0 + 16 * Kd, sAp + 16 * 32);
        async_load16(Wg + k0, sBp);
        async_load16(Wg + k0 + 16 * Kd, sBp + 16 * 32);
        __syncthreads();
        bf16x8 af[4], bfr[4];
#pragma unroll
        for (int i = 0; i < 4; i++)
            af[i] = *(const bf16x8*)&sA[(wm + i * 16 + lcol) * 32 + quad * 8];
#pragma unroll
        for (int i = 0; i < 4; i++)
            bfr[i] = *(const bf16x8*)&sB[(wn + i * 16 + lcol) * 32 + quad * 8];
#pragma unroll
        for (int i = 0; i < 4; i++)
#pragma unroll
            for (int j = 0; j < 4; j++)
                acc[i][j] = MFMA_BF16(af[i], bfr[j], acc[i][j]);
    }
#pragma unroll
    for (int j = 0; j < 4; j++) {
        int n = n0 + wn + j * 16 + lcol;
        float bv = bias[n];
        int part = n >> 10, d = n & 1023, h = d >> 6, dd = d & 63;
#pragma unroll
        for (int i = 0; i < 4; i++) {
            int mb = m0 + wm + i * 16 + quad * 4;
            int b = mb >> 10, s = mb & 1023;
            if (part == 2) {
                bf16x4 v4;
#pragma unroll
                for (int r = 0; r < 4; r++) v4[r] = (bf16)(acc[i][j][r] + bv);
                *(bf16x4*)&Vt[(size_t)((b * 16 + h) * 64 + dd) * 1024 + s] = v4;
            } else {
                float scv = (part == 0) ? 0.125f : 1.0f;
                bf16* dst = (part == 0 ? Qb : Kb) + (size_t)((b * 16 + h) * 1024 + s) * 64 + dd;
#pragma unroll
                for (int r = 0; r < 4; r++) dst[(size_t)r * 64] = (bf16)((acc[i][j][r] + bv) * scv);
            }
        }
    }
}

// ---------------- out-proj GEMM (async staging) ----------------
__global__ __launch_bounds__(256) void gemm_out_kernel(
    const bf16* __restrict__ A, const bf16* __restrict__ W,
    const float* __restrict__ bias, float* __restrict__ out)
{
    const int Kd = 1024;
    __shared__ bf16 sA[128 * 32];
    __shared__ bf16 sB[128 * 32];
    int tid = threadIdx.x, lane = tid & 63, wid = tid >> 6;
    int m0 = blockIdx.y * 128, n0 = blockIdx.x * 128;
    int srow = wid * 32 + (lane >> 2);
    int scol = (lane & 3) * 8;
    const bf16* Ag = A + (size_t)(m0 + srow) * Kd + scol;
    const bf16* Wg = W + (size_t)(n0 + srow) * Kd + scol;
    bf16* sAp = &sA[srow * 32 + scol];
    bf16* sBp = &sB[srow * 32 + scol];
    int wm = (wid & 1) * 64, wn = (wid >> 1) * 64;
    int lcol = lane & 15, quad = lane >> 4;
    f32x4 acc[4][4] = {};
    for (int k0 = 0; k0 < Kd; k0 += 32) {
        __syncthreads();
        async_load16(Ag + k0, sAp);
        async_load16(Ag + k0 + 16 * Kd, sAp + 16 * 32);
        async_load16(Wg + k0, sBp);
        async_load16(Wg + k0 + 16 * Kd, sBp + 16 * 32);
        __syncthreads();
        bf16x8 af[4], bfr[4];
#pragma unroll
        for (int i = 0; i < 4; i++)
            af[i] = *(const bf16x8*)&sA[(wm + i * 16 + lcol) * 32 + quad * 8];
#pragma unroll
        for (int i = 0; i < 4; i++)
            bfr[i] = *(const bf16x8*)&sB[(wn + i * 16 + lcol) * 32 + quad * 8];
#pragma unroll
        for (int i = 0; i < 4; i++)
#pragma unroll
            for (int j = 0; j < 4; j++)
                acc[i][j] = MFMA_BF16(af[i], bfr[j], acc[i][j]);
    }
#pragma unroll
    for (int j = 0; j < 4; j++) {
        int n = n0 + wn + j * 16 + lcol;
        float bv = bias[n];
#pragma unroll
        for (int i = 0; i < 4; i++) {
            int m = m0 + wm + i * 16 + quad * 4;
#pragma unroll
            for (int r = 0; r < 4; r++) out[(size_t)(m + r) * 1024 + n] = acc[i][j][r] + bv;
        }
    }
}

// ---------------- flash attention: one wave per (b, head, q16), ZERO barriers ----------------
// grid 1024 blocks x 256 thr: hg = bx&3, q0 = ((bx>>2)&63)*16, b = bx>>8; wave wid -> head hg*4+wid.
// Online softmax over 32-key tiles; wave-private LDS transpose tile; writes ctx + (m,l).
__global__ __launch_bounds__(256) void flash_kernel(
    const bf16* __restrict__ Qb, const bf16* __restrict__ Kb, const bf16* __restrict__ Vt,
    bf16* __restrict__ ctx, float2* __restrict__ ml)
{
    __shared__ bf16 pt[4 * 512];  // per-wave 16x32 transpose tile
    int tid = threadIdx.x, lane = tid & 63, wid = tid >> 6;
    int bx = blockIdx.x;
    int hg = bx & 3;
    int q0 = ((bx >> 2) & 63) * 16;
    int b = bx >> 8;
    int h = hg * 4 + wid;
    int lcol = lane & 15, quad = lane >> 4;
    size_t base = (size_t)(b * 16 + h) * 65536;

    const bf16* qp = Qb + base + (size_t)(q0 + lcol) * 64 + quad * 8;
    bf16x8 a0 = *(const bf16x8*)qp;
    bf16x8 a1 = *(const bf16x8*)(qp + 32);
    bf16* wp = pt + wid * 512;

    float m_[4] = {-1e30f, -1e30f, -1e30f, -1e30f};
    float l_[4] = {0.f, 0.f, 0.f, 0.f};
    f32x4 o[4] = {};

    for (int kt = 0; kt < 32; kt++) {
        // S tile 16q x 32k
        const bf16* kr0 = Kb + base + (size_t)(kt * 32 + lcol) * 64 + quad * 8;
        const bf16* kr1 = kr0 + 16 * 64;
        bf16x8 b0 = *(const bf16x8*)kr0;
        bf16x8 b1 = *(const bf16x8*)(kr0 + 32);
        bf16x8 b2 = *(const bf16x8*)kr1;
        bf16x8 b3 = *(const bf16x8*)(kr1 + 32);
        f32x4 s1 = {}, s2 = {};
        s1 = MFMA_BF16(a0, b0, s1); s1 = MFMA_BF16(a1, b1, s1);
        s2 = MFMA_BF16(a0, b2, s2); s2 = MFMA_BF16(a1, b3, s2);
        // row-tile max (butterfly over the 16 col-lanes)
        float tmax[4];
#pragma unroll
        for (int rr = 0; rr < 4; rr++) tmax[rr] = fmaxf(s1[rr], s2[rr]);
#pragma unroll
        for (int mk = 1; mk < 16; mk <<= 1)
#pragma unroll
            for (int rr = 0; rr < 4; rr++) tmax[rr] = fmaxf(tmax[rr], __shfl_xor(tmax[rr], mk, 64));
        float alpha[4], p1[4], p2[4];
#pragma unroll
        for (int rr = 0; rr < 4; rr++) {
            float mn = fmaxf(m_[rr], tmax[rr]);
            alpha[rr] = __expf(m_[rr] - mn);
            p1[rr] = __expf(s1[rr] - mn);
            p2[rr] = __expf(s2[rr] - mn);
            m_[rr] = mn;
            l_[rr] = l_[rr] * alpha[rr] + p1[rr] + p2[rr];
        }
#pragma unroll
        for (int dt = 0; dt < 4; dt++)
#pragma unroll
            for (int rr = 0; rr < 4; rr++) o[dt][rr] *= alpha[rr];
        // transpose P via wave-private LDS (C-layout -> A-layout)
#pragma unroll
        for (int rr = 0; rr < 4; rr++) {
            wp[(quad * 4 + rr) * 32 + lcol]      = (bf16)p1[rr];
            wp[(quad * 4 + rr) * 32 + lcol + 16] = (bf16)p2[rr];
        }
        bf16x8 pa = *(const bf16x8*)&wp[lcol * 32 + quad * 8];
        // PV
#pragma unroll
        for (int dt = 0; dt < 4; dt++) {
            bf16x8 vb = *(const bf16x8*)(Vt + base + (size_t)(dt * 16 + lcol) * 1024 + kt * 32 + quad * 8);
            o[dt] = MFMA_BF16(pa, vb, o[dt]);
        }
    }
    // final l: butterfly sum over col-lanes
    float lt[4];
#pragma unroll
    for (int rr = 0; rr < 4; rr++) lt[rr] = l_[rr];
#pragma unroll
    for (int mk = 1; mk < 16; mk <<= 1)
#pragma unroll
        for (int rr = 0; rr < 4; rr++) lt[rr] += __shfl_xor(lt[rr], mk, 64);
#pragma unroll
    for (int rr = 0; rr < 4; rr++) {
        float inv = 1.f / lt[rr];
#pragma unroll
        for (int dt = 0; dt < 4; dt++)
            ctx[(size_t)(b * 1024 + q0 + quad * 4 + rr) * 1024 + h * 64 + dt * 16 + lcol] =
                (bf16)(o[dt][rr] * inv);
    }
    if (lcol == 0) {
#pragma unroll
        for (int rr = 0; rr < 4; rr++)
            ml[(size_t)(b * 16 + h) * 1024 + q0 + quad * 4 + rr] = make_float2(m_[rr], lt[rr]);
    }
}

// ---------------- attn-weights: recompute QK^T, aw = sum_h exp(s-m)/l/16 (fp32, direct) ----------------
// grid 512: kh = bx&1, q0 = ((bx>>1)&63)*16, b = bx>>7; wave keys [kh*512+wid*128, +128). ZERO barriers.
__global__ __launch_bounds__(256) void aw_kernel(
    const bf16* __restrict__ Qb, const bf16* __restrict__ Kb,
    const float2* __restrict__ ml, float* __restrict__ aw)
{
    int tid = threadIdx.x, lane = tid & 63, wid = tid >> 6;
    int bx = blockIdx.x;
    int kh = bx & 1;
    int q0 = ((bx >> 1) & 63) * 16;
    int b = bx >> 7;
    int lcol = lane & 15, quad = lane >> 4;
    int kbase = kh * 512 + wid * 128;
    float acc[32];
#pragma unroll
    for (int i = 0; i < 32; i++) acc[i] = 0.f;

    for (int h = 0; h < 16; h++) {
        size_t base = (size_t)(b * 16 + h) * 65536;
        const bf16* qp = Qb + base + (size_t)(q0 + lcol) * 64 + quad * 8;
        bf16x8 a0 = *(const bf16x8*)qp;
        bf16x8 a1 = *(const bf16x8*)(qp + 32);
        float mrow[4], scale[4];
#pragma unroll
        for (int rr = 0; rr < 4; rr++) {
            float2 v = ml[(size_t)(b * 16 + h) * 1024 + q0 + quad * 4 + rr];
            mrow[rr] = v.x;
            scale[rr] = 0.0625f / v.y;
        }
#pragma unroll
        for (int nt = 0; nt < 8; nt++) {
            const bf16* kr = Kb + base + (size_t)(kbase + nt * 16 + lcol) * 64 + quad * 8;
            bf16x8 b0 = *(const bf16x8*)kr;
            bf16x8 b1 = *(const bf16x8*)(kr + 32);
            f32x4 s = {};
            s = MFMA_BF16(a0, b0, s);
            s = MFMA_BF16(a1, b1, s);
#pragma unroll
            for (int rr = 0; rr < 4; rr++)
                acc[nt * 4 + rr] += __expf(s[rr] - mrow[rr]) * scale[rr];
        }
    }
#pragma unroll
    for (int nt = 0; nt < 8; nt++)
#pragma unroll
        for (int rr = 0; rr < 4; rr++)
            aw[(size_t)(b * 1024 + q0 + quad * 4 + rr) * 1024 + kbase + nt * 16 + lcol] = acc[nt * 4 + rr];
}

// ---------------- residual + LayerNorm (fp32 output) ----------------
__global__ __launch_bounds__(256) void ln_kernel(
    const float* __restrict__ x, const float* __restrict__ ao,
    const float* __restrict__ w, const float* __restrict__ bsh,
    float* __restrict__ y)
{
    int row = blockIdx.x, tid = threadIdx.x;
    float4 xv = ((const float4*)(x + (size_t)row * 1024))[tid];
    float4 av = ((const float4*)(ao + (size_t)row * 1024))[tid];
    float4 v = {xv.x + av.x, xv.y + av.y, xv.z + av.z, xv.w + av.w};
    float s = v.x + v.y + v.z + v.w;
    float ss = v.x * v.x + v.y * v.y + v.z * v.z + v.w * v.w;
#pragma unroll
    for (int off = 32; off; off >>= 1) { s += __shfl_down(s, off); ss += __shfl_down(ss, off); }
    __shared__ float rs[4], rss[4];
    int lane = tid & 63, wid = tid >> 6;
    if (lane == 0) { rs[wid] = s; rss[wid] = ss; }
    __syncthreads();
    s = rs[0] + rs[1] + rs[2] + rs[3];
    ss = rss[0] + rss[1] + rss[2] + rss[3];
    float mean = s * (1.f / 1024.f);
    float var = ss * (1.f / 1024.f) - mean * mean;
    float inv = rsqrtf(var + 1e-5f);
    float4 wv = ((const float4*)w)[tid];
    float4 bv = ((const float4*)bsh)[tid];
    float4 o;
    o.x = (v.x - mean) * inv * wv.x + bv.x;
    o.y = (v.y - mean) * inv * wv.y + bv.y;
    o.z = (v.z - mean) * inv * wv.z + bv.z;
    o.w = (v.w - mean) * inv * wv.w + bv.w;
    ((float4*)y)[row * 256 + tid] = o;
}

extern "C" void kernel_launch(void* const* d_in, const int* in_sizes, int n_in,
                              void* d_out, int out_size, void* d_ws, size_t ws_size,
                              hipStream_t stream) {
    const float* x     = (const float*)d_in[0];
    const float* w_qkv = (const float*)d_in[1];
    const float* b_qkv = (const float*)d_in[2];
    const float* w_out = (const float*)d_in[3];
    const float* b_out = (const float*)d_in[4];
    const float* ln_w  = (const float*)d_in[5];
    const float* ln_b  = (const float*)d_in[6];

    char* ws = (char*)d_ws;
    // [0,8M) Qb | [8,16M) Kb | [16,24M) Vt | [24,32M) ctx | [32,32.5M) ml |
    // x_bf [33,41M), wq_bf [41,47M) live only until gemm_qkv;
    // wo_bf [16,18M) after aw (Vt dead); ao fp32 [0,16M) after aw (Qb/Kb dead).
    bf16*   Qb    = (bf16*)(ws);
    bf16*   Kb    = (bf16*)(ws + (8ull  << 20));
    bf16*   Vt    = (bf16*)(ws + (16ull << 20));
    bf16*   ctx   = (bf16*)(ws + (24ull << 20));
    float2* ml    = (float2*)(ws + (32ull << 20));
    bf16*   x_bf  = (bf16*)(ws + (33ull << 20));
    bf16*   wq_bf = (bf16*)(ws + (41ull << 20));
    bf16*   wo_bf = (bf16*)(ws + (16ull << 20));
    float*  ao    = (float*)(ws);

    float* y_out  = (float*)d_out;
    float* aw_out = y_out + 4ull * 1024 * 1024;

    cvt_kernel<<<4096, 256, 0, stream>>>(x, x_bf, 1048576);
    cvt_kernel<<<3072, 256, 0, stream>>>(w_qkv, wq_bf, 786432);
    gemm_qkv_kernel<<<dim3(24, 32), 256, 0, stream>>>(x_bf, wq_bf, b_qkv, Qb, Kb, Vt);
    flash_kernel<<<1024, 256, 0, stream>>>(Qb, Kb, Vt, ctx, ml);
    aw_kernel<<<512, 256, 0, stream>>>(Qb, Kb, ml, aw_out);
    cvt_kernel<<<1024, 256, 0, stream>>>(w_out, wo_bf, 262144);
    gemm_out_kernel<<<dim3(8, 32), 256, 0, stream>>>(ctx, wo_bf, b_out, ao);
    ln_kernel<<<4096, 256, 0, stream>>>(x, ao, ln_w, ln_b, y_out);
}